// Round 1
// baseline (665.239 us; speedup 1.0000x reference)
//
#include <hip/hip_runtime.h>

typedef unsigned short u16;
typedef float f32x4 __attribute__((ext_vector_type(4)));
typedef __bf16 bf16x8 __attribute__((ext_vector_type(8)));

#define S_LEN 2048
#define DMODEL 1024
#define NHEAD 16
#define DKH 64
#define LDP 40   // padded LDS row (32 data + 8 pad) in u16; 80B rows -> even ds_read_b128 bank spread

__device__ __forceinline__ u16 f2bf(float f) {
    unsigned u = __float_as_uint(f);
    u += 0x7FFFu + ((u >> 16) & 1u);   // RNE
    return (u16)(u >> 16);
}

// ---------------- fp32 -> bf16 convert ----------------
__global__ __launch_bounds__(256) void cvt_kernel(const float* __restrict__ in,
                                                  u16* __restrict__ out, int n4) {
    int i = blockIdx.x * 256 + threadIdx.x;
    if (i >= n4) return;
    float4 v = reinterpret_cast<const float4*>(in)[i];
    uint2 o;
    o.x = (unsigned)f2bf(v.x) | ((unsigned)f2bf(v.y) << 16);
    o.y = (unsigned)f2bf(v.z) | ((unsigned)f2bf(v.w) << 16);
    reinterpret_cast<uint2*>(out)[i] = o;
}

// ---------------- shared GEMM core: C = A * Bt^T (both bf16, K-contiguous rows) ----------------
// 128x128 tile, BK=32, 256 threads (4 waves, each wave a 64x64 quadrant = 4x4 mfma tiles).
__device__ __forceinline__ void gemm_core(const u16* __restrict__ A, const u16* __restrict__ Bt,
                                          int K, int m0, int n0,
                                          u16* As, u16* Bs, f32x4 acc[4][4]) {
    const int tid  = threadIdx.x;
    const int lane = tid & 63;
    const int quad = lane >> 4, l15 = lane & 15;
    const int w    = tid >> 6;
    const int mq   = w & 1, nq = w >> 1;
    const int srow = tid >> 2;            // 0..63
    const int scol = (tid & 3) * 8;       // element offset (16B chunks)

    const u16* ag0 = A  + (size_t)(m0 + srow)      * K + scol;
    const u16* ag1 = A  + (size_t)(m0 + 64 + srow) * K + scol;
    const u16* bg0 = Bt + (size_t)(n0 + srow)      * K + scol;
    const u16* bg1 = Bt + (size_t)(n0 + 64 + srow) * K + scol;
    u16* aw0 = As + srow * LDP + scol;
    u16* aw1 = As + (64 + srow) * LDP + scol;
    u16* bw0 = Bs + srow * LDP + scol;
    u16* bw1 = Bs + (64 + srow) * LDP + scol;

    for (int kk = 0; kk < K; kk += 32) {
        uint4 ra0 = *reinterpret_cast<const uint4*>(ag0 + kk);
        uint4 ra1 = *reinterpret_cast<const uint4*>(ag1 + kk);
        uint4 rb0 = *reinterpret_cast<const uint4*>(bg0 + kk);
        uint4 rb1 = *reinterpret_cast<const uint4*>(bg1 + kk);
        __syncthreads();
        *reinterpret_cast<uint4*>(aw0) = ra0;
        *reinterpret_cast<uint4*>(aw1) = ra1;
        *reinterpret_cast<uint4*>(bw0) = rb0;
        *reinterpret_cast<uint4*>(bw1) = rb1;
        __syncthreads();
        bf16x8 af[4], bfv[4];
#pragma unroll
        for (int t = 0; t < 4; ++t) {
            af[t]  = *reinterpret_cast<const bf16x8*>(As + (mq*64 + t*16 + l15) * LDP + quad*8);
            bfv[t] = *reinterpret_cast<const bf16x8*>(Bs + (nq*64 + t*16 + l15) * LDP + quad*8);
        }
#pragma unroll
        for (int mt = 0; mt < 4; ++mt)
#pragma unroll
            for (int nt = 0; nt < 4; ++nt)
                acc[mt][nt] = __builtin_amdgcn_mfma_f32_16x16x32_bf16(af[mt], bfv[nt], acc[mt][nt], 0, 0, 0);
    }
}

// ---------------- QKV projection + RoPE epilogue ----------------
// Wqkv = [P_Q; P_K; P_V] rows (3072 x 1024). Q,K -> (B,H,S,dk) with RoPE; V -> (B,H,dk,S).
__global__ __launch_bounds__(256) void gemm_qkv_kernel(const u16* __restrict__ xb, const u16* __restrict__ Wqkv,
                                                       u16* __restrict__ Qb, u16* __restrict__ Kb,
                                                       u16* __restrict__ Vt) {
    __shared__ u16 As[128 * LDP];
    __shared__ u16 Bs[128 * LDP];
    f32x4 acc[4][4];
    const f32x4 zz = {0.f, 0.f, 0.f, 0.f};
#pragma unroll
    for (int i = 0; i < 4; ++i)
#pragma unroll
        for (int j = 0; j < 4; ++j) acc[i][j] = zz;

    const int m0 = blockIdx.y * 128;
    const int n0 = blockIdx.x * 128;
    gemm_core(xb, Wqkv, DMODEL, m0, n0, As, Bs, acc);

    const int lane = threadIdx.x & 63;
    const int quad = lane >> 4, l15 = lane & 15;
    const int w = threadIdx.x >> 6, mq = w & 1, nq = w >> 1;

#pragma unroll
    for (int nt = 0; nt < 4; ++nt) {
        const int ncol = n0 + nq*64 + nt*16 + l15;
        const int sel  = ncol >> 10;         // 0=Q,1=K,2=V (wave-uniform: 16-col tile within 1024 block)
        const int e    = ncol & 1023;
        const int h    = e >> 6, dk = e & 63;
#pragma unroll
        for (int mt = 0; mt < 4; ++mt) {
            const int mrow = m0 + mq*64 + mt*16 + quad*4;
            if (sel == 2) {
#pragma unroll
                for (int r = 0; r < 4; ++r) {
                    int m = mrow + r;
                    int b = m >> 11, s = m & 2047;
                    Vt[((size_t)(b * NHEAD + h) * DKH + dk) * S_LEN + s] = f2bf(acc[mt][nt][r]);
                }
            } else {
                // inv_freq = theta^(-(2i)/64), 2i = dk & ~1 ; log2(10000)=13.2877124
                float invf = exp2f(-13.2877124f * (float)(dk & 62) * (1.0f / 64.0f));
                u16* dst = sel ? Kb : Qb;
#pragma unroll
                for (int r = 0; r < 4; ++r) {
                    float val  = acc[mt][nt][r];
                    float part = __shfl_xor(val, 1);   // partner feature e^1 (same pair)
                    int m = mrow + r;
                    int b = m >> 11, s = m & 2047;
                    float ang = (float)s * invf;
                    float sn, cs;
                    __sincosf(ang, &sn, &cs);
                    float o = (dk & 1) ? (part * sn + val * cs)   // odd: x1*sin + x2*cos
                                       : (val * cs - part * sn);  // even: x1*cos - x2*sin
                    dst[((size_t)(b * NHEAD + h) * S_LEN + s) * DKH + dk] = f2bf(o);
                }
            }
        }
    }
}

// ---------------- flash attention: one wave per 16 q-rows, 32 keys/iter ----------------
__global__ __launch_bounds__(256) void attn_kernel(const u16* __restrict__ Qb, const u16* __restrict__ Kb,
                                                   const u16* __restrict__ Vt, u16* __restrict__ A2) {
    const int lane = threadIdx.x & 63;
    const int wv   = threadIdx.x >> 6;
    const int gw   = blockIdx.x * 4 + wv;
    const int bh   = gw >> 7;              // 0..63
    const int qt   = gw & 127;
    const int q0   = qt << 4;
    const int quad = lane >> 4, l15 = lane & 15;
    const int b = bh >> 4, h = bh & 15;

    const u16* qrow = Qb + ((size_t)bh * S_LEN + q0 + l15) * DKH;
    bf16x8 qA = *reinterpret_cast<const bf16x8*>(qrow + quad * 8);
    bf16x8 qB = *reinterpret_cast<const bf16x8*>(qrow + 32 + quad * 8);

    const f32x4 zz = {0.f, 0.f, 0.f, 0.f};
    f32x4 o[4];
#pragma unroll
    for (int nt = 0; nt < 4; ++nt) o[nt] = zz;
    float m_i = -3.0e38f, l_i = 0.f;
    const float csc = 0.125f * 1.44269504f;  // (1/sqrt(64)) * log2(e)
    const int q_my = q0 + l15;
    const int ktiles = (q0 + 47) >> 5;

    for (int kt = 0; kt < ktiles; ++kt) {
        const int key0 = kt << 5;
        const u16* krow0 = Kb + ((size_t)bh * S_LEN + key0 + l15) * DKH;
        const u16* krow1 = krow0 + 16 * DKH;
        bf16x8 k0a = *reinterpret_cast<const bf16x8*>(krow0 + quad*8);
        bf16x8 k0b = *reinterpret_cast<const bf16x8*>(krow0 + 32 + quad*8);
        bf16x8 k1a = *reinterpret_cast<const bf16x8*>(krow1 + quad*8);
        bf16x8 k1b = *reinterpret_cast<const bf16x8*>(krow1 + 32 + quad*8);

        // S^T = K * Q^T : rows=keys(quad*4+r), cols=q(l15)
        f32x4 st0 = __builtin_amdgcn_mfma_f32_16x16x32_bf16(k0a, qA, zz, 0, 0, 0);
        st0 = __builtin_amdgcn_mfma_f32_16x16x32_bf16(k0b, qB, st0, 0, 0, 0);
        f32x4 st1 = __builtin_amdgcn_mfma_f32_16x16x32_bf16(k1a, qA, zz, 0, 0, 0);
        st1 = __builtin_amdgcn_mfma_f32_16x16x32_bf16(k1b, qB, st1, 0, 0, 0);

        float sv[8];
#pragma unroll
        for (int r = 0; r < 4; ++r) { sv[r] = st0[r]; sv[4 + r] = st1[r]; }
        if (kt == ktiles - 1) {
#pragma unroll
            for (int t = 0; t < 2; ++t)
#pragma unroll
                for (int r = 0; r < 4; ++r) {
                    int key = key0 + t*16 + quad*4 + r;
                    if (key > q_my) sv[t*4 + r] = -3.0e38f;
                }
        }
        // softmax row (= q = l15) reduction across quads
        float rm = sv[0];
#pragma unroll
        for (int j = 1; j < 8; ++j) rm = fmaxf(rm, sv[j]);
        rm = fmaxf(rm, __shfl_xor(rm, 16));
        rm = fmaxf(rm, __shfl_xor(rm, 32));
        float m_new = fmaxf(m_i, rm);
        float alpha = exp2f((m_i - m_new) * csc);
        float p[8]; float rs = 0.f;
#pragma unroll
        for (int j = 0; j < 8; ++j) { p[j] = exp2f((sv[j] - m_new) * csc); rs += p[j]; }
        rs += __shfl_xor(rs, 16);
        rs += __shfl_xor(rs, 32);
        l_i = l_i * alpha + rs;
        m_i = m_new;
        // rescale O accumulator (rows are q = quad*4+r in C/D layout)
#pragma unroll
        for (int r = 0; r < 4; ++r) {
            float ar = __shfl(alpha, (lane & 48) + quad*4 + r);
            o[0][r] *= ar; o[1][r] *= ar; o[2][r] *= ar; o[3][r] *= ar;
        }
        // transpose P from S^T C/D layout into A-operand layout via bpermute shuffles
        float pa[8];
#pragma unroll
        for (int j = 0; j < 8; ++j) {
            int key_l = quad*8 + j;
            int src = (((key_l & 15) >> 2) << 4) | l15;
            float v0 = __shfl(p[j & 3], src);
            float v1 = __shfl(p[4 + (j & 3)], src);
            pa[j] = (key_l < 16) ? v0 : v1;
        }
        bf16x8 pf;
#pragma unroll
        for (int j = 0; j < 8; ++j) pf[j] = (__bf16)pa[j];
        // O += P * V  (V^T stored (B,H,dk,S): contiguous along keys)
#pragma unroll
        for (int nt = 0; nt < 4; ++nt) {
            const u16* vrow = Vt + ((size_t)bh * DKH + nt*16 + l15) * S_LEN + key0 + quad*8;
            bf16x8 vf = *reinterpret_cast<const bf16x8*>(vrow);
            o[nt] = __builtin_amdgcn_mfma_f32_16x16x32_bf16(pf, vf, o[nt], 0, 0, 0);
        }
    }

    float inv_l = 1.0f / l_i;
#pragma unroll
    for (int r = 0; r < 4; ++r) {
        float ilr = __shfl(inv_l, (lane & 48) + quad*4 + r);
        int s = q0 + quad*4 + r;
#pragma unroll
        for (int nt = 0; nt < 4; ++nt) {
            A2[((size_t)b * S_LEN + s) * DMODEL + h*DKH + nt*16 + l15] = f2bf(o[nt][r] * ilr);
        }
    }
}

// ---------------- output projection ----------------
__global__ __launch_bounds__(256) void gemm_oproj_kernel(const u16* __restrict__ A2, const u16* __restrict__ Wo,
                                                         float* __restrict__ Cout) {
    __shared__ u16 As[128 * LDP];
    __shared__ u16 Bs[128 * LDP];
    f32x4 acc[4][4];
    const f32x4 zz = {0.f, 0.f, 0.f, 0.f};
#pragma unroll
    for (int i = 0; i < 4; ++i)
#pragma unroll
        for (int j = 0; j < 4; ++j) acc[i][j] = zz;

    const int m0 = blockIdx.y * 128;
    const int n0 = blockIdx.x * 128;
    gemm_core(A2, Wo, DMODEL, m0, n0, As, Bs, acc);

    const int lane = threadIdx.x & 63;
    const int quad = lane >> 4, l15 = lane & 15;
    const int w = threadIdx.x >> 6, mq = w & 1, nq = w >> 1;
#pragma unroll
    for (int nt = 0; nt < 4; ++nt) {
        const int ncol = n0 + nq*64 + nt*16 + l15;
#pragma unroll
        for (int mt = 0; mt < 4; ++mt) {
            const int mrow = m0 + mq*64 + mt*16 + quad*4;
#pragma unroll
            for (int r = 0; r < 4; ++r)
                Cout[(size_t)(mrow + r) * DMODEL + ncol] = acc[mt][nt][r];
        }
    }
}

extern "C" void kernel_launch(void* const* d_in, const int* in_sizes, int n_in,
                              void* d_out, int out_size, void* d_ws, size_t ws_size,
                              hipStream_t stream) {
    const float* x  = (const float*)d_in[0];
    const float* PQ = (const float*)d_in[1];
    const float* PK = (const float*)d_in[2];
    const float* PV = (const float*)d_in[3];
    const float* PO = (const float*)d_in[4];
    float* out = (float*)d_out;
    char* ws = (char*)d_ws;

    const size_t MB = 1u << 20;
    u16* xb   = (u16*)(ws + 0 * MB);    // 16 MB  (8192x1024 bf16)
    u16* Wqkv = (u16*)(ws + 16 * MB);   // 6 MB   (3072x1024 bf16)
    u16* Wo   = (u16*)(ws + 22 * MB);   // 2 MB
    u16* Qb   = (u16*)(ws + 24 * MB);   // 16 MB  (B,H,S,dk)
    u16* Kb   = (u16*)(ws + 40 * MB);   // 16 MB
    u16* Vt   = (u16*)(ws + 56 * MB);   // 16 MB  (B,H,dk,S)
    u16* A2   = (u16*)(ws + 72 * MB);   // 16 MB  (B,S,D) attn out, bf16

    // converts
    cvt_kernel<<<dim3(8192), dim3(256), 0, stream>>>(x,  xb,            2097152);
    cvt_kernel<<<dim3(1024), dim3(256), 0, stream>>>(PQ, Wqkv,           262144);
    cvt_kernel<<<dim3(1024), dim3(256), 0, stream>>>(PK, Wqkv + 1048576, 262144);
    cvt_kernel<<<dim3(1024), dim3(256), 0, stream>>>(PV, Wqkv + 2097152, 262144);
    cvt_kernel<<<dim3(1024), dim3(256), 0, stream>>>(PO, Wo,             262144);

    // QKV projection + RoPE (M=8192, N=3072, K=1024)
    gemm_qkv_kernel<<<dim3(24, 64), dim3(256), 0, stream>>>(xb, Wqkv, Qb, Kb, Vt);

    // flash attention: 8192 wave-tiles / 4 waves per block
    attn_kernel<<<dim3(2048), dim3(256), 0, stream>>>(Qb, Kb, Vt, A2);

    // output projection (M=8192, N=1024, K=1024), fp32 out
    gemm_oproj_kernel<<<dim3(8, 64), dim3(256), 0, stream>>>(A2, Wo, out);
}

// Round 2
// 314.296 us; speedup vs baseline: 2.1166x; 2.1166x over previous
//
#include <hip/hip_runtime.h>

typedef unsigned short u16;
typedef unsigned int u32;
typedef float f32x4 __attribute__((ext_vector_type(4)));
typedef __bf16 bf16x8 __attribute__((ext_vector_type(8)));

#define S_LEN 2048
#define DMODEL 1024
#define NHEAD 16
#define DKH 64

__device__ __forceinline__ u16 f2bf(float f) {
    unsigned u = __float_as_uint(f);
    u += 0x7FFFu + ((u >> 16) & 1u);   // RNE
    return (u16)(u >> 16);
}
__device__ __forceinline__ u32 pk2(float a, float b) {
    return (u32)f2bf(a) | ((u32)f2bf(b) << 16);
}

// async global->LDS, 16B per lane. LDS dest must be wave-uniform base + lane*16.
__device__ __forceinline__ void glds16(const u16* g, u16* l) {
    __builtin_amdgcn_global_load_lds(
        (const __attribute__((address_space(1))) void*)(g),
        (__attribute__((address_space(3))) void*)(l), 16, 0, 0);
}

// ---------------- fp32 -> bf16 convert ----------------
__global__ __launch_bounds__(256) void cvt_kernel(const float* __restrict__ in,
                                                  u16* __restrict__ out, int n4) {
    int i = blockIdx.x * 256 + threadIdx.x;
    if (i >= n4) return;
    float4 v = reinterpret_cast<const float4*>(in)[i];
    uint2 o;
    o.x = (unsigned)f2bf(v.x) | ((unsigned)f2bf(v.y) << 16);
    o.y = (unsigned)f2bf(v.z) | ((unsigned)f2bf(v.w) << 16);
    reinterpret_cast<uint2*>(out)[i] = o;
}

// ---------------- GEMM core: C = A * Bt^T, 128x128 tile, BK=32 ----------------
// global_load_lds staging, XOR-swizzled 16B chunks (4 chunks/row of 32 elems).
__device__ __forceinline__ void gemm_core(const u16* __restrict__ A, const u16* __restrict__ Bt,
                                          int K, int m0, int n0,
                                          u16* As, u16* Bs, f32x4 acc[4][4]) {
    const int tid  = threadIdx.x;
    const int lane = tid & 63;
    const int quad = lane >> 4, l15 = lane & 15;
    const int w    = tid >> 6;
    const int mq   = w & 1, nq = w >> 1;

    // staging: chunk id c -> row=c>>2, swizzled source chunk (c&3)^(row&3)
    const int c0 = tid, c1 = tid + 256;
    const int r0 = c0 >> 2, k0 = ((c0 & 3) ^ (r0 & 3)) * 8;
    const int r1 = c1 >> 2, k1 = ((c1 & 3) ^ (r1 & 3)) * 8;
    const u16* ga0 = A  + (size_t)(m0 + r0) * K + k0;
    const u16* ga1 = A  + (size_t)(m0 + r1) * K + k1;
    const u16* gb0 = Bt + (size_t)(n0 + r0) * K + k0;
    const u16* gb1 = Bt + (size_t)(n0 + r1) * K + k1;
    u16* la0 = As + c0 * 8; u16* la1 = As + c1 * 8;
    u16* lb0 = Bs + c0 * 8; u16* lb1 = Bs + c1 * 8;

    const int swz = (quad ^ (l15 & 3)) * 8;
    const u16* ra = As + (mq * 64 + l15) * 32 + swz;
    const u16* rb = Bs + (nq * 64 + l15) * 32 + swz;

    for (int kk = 0; kk < K; kk += 32) {
        __syncthreads();
        glds16(ga0 + kk, la0);
        glds16(ga1 + kk, la1);
        glds16(gb0 + kk, lb0);
        glds16(gb1 + kk, lb1);
        __syncthreads();
        bf16x8 af[4], bfv[4];
#pragma unroll
        for (int t = 0; t < 4; ++t) {
            af[t]  = *reinterpret_cast<const bf16x8*>(ra + t * 512);
            bfv[t] = *reinterpret_cast<const bf16x8*>(rb + t * 512);
        }
#pragma unroll
        for (int mt = 0; mt < 4; ++mt)
#pragma unroll
            for (int nt = 0; nt < 4; ++nt)
                acc[mt][nt] = __builtin_amdgcn_mfma_f32_16x16x32_bf16(af[mt], bfv[nt], acc[mt][nt], 0, 0, 0);
    }
}

// ---------------- QKV projection + RoPE epilogue ----------------
__global__ __launch_bounds__(256) void gemm_qkv_kernel(const u16* __restrict__ xb, const u16* __restrict__ Wqkv,
                                                       u16* __restrict__ Qb, u16* __restrict__ Kb,
                                                       u16* __restrict__ Vt) {
    __shared__ u16 As[128 * 32];
    __shared__ u16 Bs[128 * 32];
    f32x4 acc[4][4];
    const f32x4 zz = {0.f, 0.f, 0.f, 0.f};
#pragma unroll
    for (int i = 0; i < 4; ++i)
#pragma unroll
        for (int j = 0; j < 4; ++j) acc[i][j] = zz;

    const int m0 = blockIdx.y * 128;
    const int n0 = blockIdx.x * 128;
    gemm_core(xb, Wqkv, DMODEL, m0, n0, As, Bs, acc);

    const int lane = threadIdx.x & 63;
    const int quad = lane >> 4, l15 = lane & 15;
    const int w = threadIdx.x >> 6, mq = w & 1, nq = w >> 1;

#pragma unroll
    for (int nt = 0; nt < 4; ++nt) {
        const int ncol = n0 + nq*64 + nt*16 + l15;
        const int sel  = ncol >> 10;         // 0=Q,1=K,2=V (wave-uniform)
        const int e    = ncol & 1023;
        const int h    = e >> 6, dk = e & 63;
#pragma unroll
        for (int mt = 0; mt < 4; ++mt) {
            const int mrow = m0 + mq*64 + mt*16 + quad*4;
            if (sel == 2) {
#pragma unroll
                for (int r = 0; r < 4; ++r) {
                    int m = mrow + r;
                    int b = m >> 11, s = m & 2047;
                    Vt[((size_t)(b * NHEAD + h) * DKH + dk) * S_LEN + s] = f2bf(acc[mt][nt][r]);
                }
            } else {
                float invf = exp2f(-13.2877124f * (float)(dk & 62) * (1.0f / 64.0f));
                u16* dst = sel ? Kb : Qb;
#pragma unroll
                for (int r = 0; r < 4; ++r) {
                    float val  = acc[mt][nt][r];
                    float part = __shfl_xor(val, 1);
                    int m = mrow + r;
                    int b = m >> 11, s = m & 2047;
                    float ang = (float)s * invf;
                    float sn, cs;
                    __sincosf(ang, &sn, &cs);
                    float o = (dk & 1) ? (part * sn + val * cs)
                                       : (val * cs - part * sn);
                    dst[((size_t)(b * NHEAD + h) * S_LEN + s) * DKH + dk] = f2bf(o);
                }
            }
        }
    }
}

// ---------------- flash attention: block = 128 q-rows, LDS-shared K/V tiles ----------------
__global__ __launch_bounds__(256) void attn_kernel(const u16* __restrict__ Qb, const u16* __restrict__ Kb,
                                                   const u16* __restrict__ Vt, u16* __restrict__ A2) {
    __shared__ u16 Ks[64 * 64];        // [key][dk-chunk swizzled]
    __shared__ u16 Vs[64 * 64];        // [dk][key-chunk swizzled] (V^T)
    __shared__ u16 Ps[4][32 * 64];     // per-wave P / O buffer, chunk-swizzled

    const int tid  = threadIdx.x;
    const int lane = tid & 63, w = tid >> 6;
    const int quad = lane >> 4, l15 = lane & 15;
    const int bh   = blockIdx.x & 63;
    const int qb   = 15 - (blockIdx.x >> 6);   // longest blocks first
    const int b = bh >> 4, h = bh & 15;
    const int q0w = qb * 128 + w * 32;
    const int nkt = 2 * (qb + 1);
    const int sw7 = l15 & 7;
    const float csc = 0.125f * 1.44269504f;
    const f32x4 zz = {0.f, 0.f, 0.f, 0.f};

    // Q fragments (B-operand: n=q=l15, k=dk=hh*32+quad*8+j), read once from global
    bf16x8 qf[2][2];
#pragma unroll
    for (int qt2 = 0; qt2 < 2; ++qt2)
#pragma unroll
        for (int hh = 0; hh < 2; ++hh)
            qf[qt2][hh] = *reinterpret_cast<const bf16x8*>(
                Qb + ((size_t)bh * S_LEN + q0w + qt2 * 16 + l15) * DKH + hh * 32 + quad * 8);

    f32x4 st[4][2], ot[4][2];
#pragma unroll
    for (int mt = 0; mt < 4; ++mt) { ot[mt][0] = zz; ot[mt][1] = zz; }
    float mi[2] = {-3.0e38f, -3.0e38f}, li[2] = {0.f, 0.f};

    // staging constants: chunk id c -> row=c>>3, swizzled src chunk (c&7)^(row&7)
    const int c0 = tid, c1 = tid + 256;
    const int r0 = c0 >> 3, kc0 = ((c0 & 7) ^ (r0 & 7)) * 8;
    const int r1 = c1 >> 3, kc1 = ((c1 & 7) ^ (r1 & 7)) * 8;
    const u16* gk0 = Kb + ((size_t)bh * S_LEN + r0) * DKH + kc0;
    const u16* gk1 = Kb + ((size_t)bh * S_LEN + r1) * DKH + kc1;
    const u16* gv0 = Vt + ((size_t)bh * DKH + r0) * S_LEN + kc0;
    const u16* gv1 = Vt + ((size_t)bh * DKH + r1) * S_LEN + kc1;
    u16* lk0 = Ks + c0 * 8; u16* lk1 = Ks + c1 * 8;
    u16* lv0 = Vs + c0 * 8; u16* lv1 = Vs + c1 * 8;
    u16* Pw = &Ps[w][0];

    for (int kt = 0; kt < nkt; ++kt) {
        const int key0 = kt * 64;
        __syncthreads();
        glds16(gk0 + (size_t)key0 * DKH, lk0);
        glds16(gk1 + (size_t)key0 * DKH, lk1);
        glds16(gv0 + key0, lv0);
        glds16(gv1 + key0, lv1);
        __syncthreads();

        // S^T = K * Q^T  (rows=keys, cols=q)
#pragma unroll
        for (int kt4 = 0; kt4 < 4; ++kt4) {
            const u16* krow = Ks + (kt4 * 16 + l15) * 64;
            bf16x8 ka0 = *reinterpret_cast<const bf16x8*>(krow + (quad ^ sw7) * 8);
            bf16x8 ka1 = *reinterpret_cast<const bf16x8*>(krow + ((4 + quad) ^ sw7) * 8);
#pragma unroll
            for (int qt2 = 0; qt2 < 2; ++qt2) {
                f32x4 s = __builtin_amdgcn_mfma_f32_16x16x32_bf16(ka0, qf[qt2][0], zz, 0, 0, 0);
                st[kt4][qt2] = __builtin_amdgcn_mfma_f32_16x16x32_bf16(ka1, qf[qt2][1], s, 0, 0, 0);
            }
        }

        // causal mask (wave-uniform branch)
        if (key0 + 63 > q0w) {
#pragma unroll
            for (int qt2 = 0; qt2 < 2; ++qt2) {
                const int qrow = q0w + qt2 * 16 + l15;
#pragma unroll
                for (int kt4 = 0; kt4 < 4; ++kt4) {
                    const int kbase = key0 + kt4 * 16 + quad * 4;
#pragma unroll
                    for (int r = 0; r < 4; ++r)
                        if (kbase + r > qrow) st[kt4][qt2][r] = -3.0e38f;
                }
            }
        }

        // online softmax per q-tile; write P to wave-private LDS (B-operand layout)
#pragma unroll
        for (int qt2 = 0; qt2 < 2; ++qt2) {
            float rm = st[0][qt2][0];
#pragma unroll
            for (int kt4 = 0; kt4 < 4; ++kt4)
#pragma unroll
                for (int r = 0; r < 4; ++r) rm = fmaxf(rm, st[kt4][qt2][r]);
            rm = fmaxf(rm, __shfl_xor(rm, 16));
            rm = fmaxf(rm, __shfl_xor(rm, 32));
            const float mn = fmaxf(mi[qt2], rm);
            const float al = exp2f((mi[qt2] - mn) * csc);
            mi[qt2] = mn;
            const float nb = mn * csc;
            float rs = 0.f;
#pragma unroll
            for (int kt4 = 0; kt4 < 4; ++kt4)
#pragma unroll
                for (int r = 0; r < 4; ++r) {
                    float p = exp2f(st[kt4][qt2][r] * csc - nb);
                    st[kt4][qt2][r] = p;
                    rs += p;
                }
            rs += __shfl_xor(rs, 16);
            rs += __shfl_xor(rs, 32);
            li[qt2] = li[qt2] * al + rs;
#pragma unroll
            for (int mt = 0; mt < 4; ++mt)
#pragma unroll
                for (int r = 0; r < 4; ++r) ot[mt][qt2][r] *= al;

            u16* prow = Pw + (qt2 * 16 + l15) * 64 + (quad & 1) * 4;
#pragma unroll
            for (int kt4 = 0; kt4 < 4; ++kt4) {
                uint2 pv;
                pv.x = pk2(st[kt4][qt2][0], st[kt4][qt2][1]);
                pv.y = pk2(st[kt4][qt2][2], st[kt4][qt2][3]);
                *reinterpret_cast<uint2*>(prow + ((2 * kt4 + (quad >> 1)) ^ sw7) * 8) = pv;
            }
        }
        __threadfence_block();   // order wave-private LDS write -> read

        // O^T += V^T * P
        bf16x8 pb[2][2];
#pragma unroll
        for (int qt2 = 0; qt2 < 2; ++qt2)
#pragma unroll
            for (int kh = 0; kh < 2; ++kh)
                pb[qt2][kh] = *reinterpret_cast<const bf16x8*>(
                    Pw + (qt2 * 16 + l15) * 64 + ((kh * 4 + quad) ^ sw7) * 8);
#pragma unroll
        for (int mt = 0; mt < 4; ++mt) {
            const u16* vrow = Vs + (mt * 16 + l15) * 64;
            bf16x8 va0 = *reinterpret_cast<const bf16x8*>(vrow + (quad ^ sw7) * 8);
            bf16x8 va1 = *reinterpret_cast<const bf16x8*>(vrow + ((4 + quad) ^ sw7) * 8);
#pragma unroll
            for (int qt2 = 0; qt2 < 2; ++qt2) {
                ot[mt][qt2] = __builtin_amdgcn_mfma_f32_16x16x32_bf16(va0, pb[qt2][0], ot[mt][qt2], 0, 0, 0);
                ot[mt][qt2] = __builtin_amdgcn_mfma_f32_16x16x32_bf16(va1, pb[qt2][1], ot[mt][qt2], 0, 0, 0);
            }
        }
    }

    // epilogue: 1/l scale, LDS transpose O^T -> [q][dk], coalesced global store
#pragma unroll
    for (int qt2 = 0; qt2 < 2; ++qt2) {
        const float il = 1.0f / li[qt2];
        u16* prow = Pw + (qt2 * 16 + l15) * 64 + (quad & 1) * 4;
#pragma unroll
        for (int mt = 0; mt < 4; ++mt) {
            uint2 ov;
            ov.x = pk2(ot[mt][qt2][0] * il, ot[mt][qt2][1] * il);
            ov.y = pk2(ot[mt][qt2][2] * il, ot[mt][qt2][3] * il);
            *reinterpret_cast<uint2*>(prow + ((2 * mt + (quad >> 1)) ^ sw7) * 8) = ov;
        }
    }
    __threadfence_block();
    const int r2 = lane >> 1, half = lane & 1;
    const u16* orow = Pw + r2 * 64;
    u16* gout = A2 + ((size_t)b * S_LEN + q0w + r2) * DMODEL + h * DKH + half * 32;
#pragma unroll
    for (int c = 0; c < 4; ++c) {
        uint4 val = *reinterpret_cast<const uint4*>(orow + (((half * 4 + c) ^ (r2 & 7))) * 8);
        *reinterpret_cast<uint4*>(gout + c * 8) = val;
    }
}

// ---------------- output projection ----------------
__global__ __launch_bounds__(256) void gemm_oproj_kernel(const u16* __restrict__ A2, const u16* __restrict__ Wo,
                                                         float* __restrict__ Cout) {
    __shared__ u16 As[128 * 32];
    __shared__ u16 Bs[128 * 32];
    f32x4 acc[4][4];
    const f32x4 zz = {0.f, 0.f, 0.f, 0.f};
#pragma unroll
    for (int i = 0; i < 4; ++i)
#pragma unroll
        for (int j = 0; j < 4; ++j) acc[i][j] = zz;

    const int m0 = blockIdx.y * 128;
    const int n0 = blockIdx.x * 128;
    gemm_core(A2, Wo, DMODEL, m0, n0, As, Bs, acc);

    const int lane = threadIdx.x & 63;
    const int quad = lane >> 4, l15 = lane & 15;
    const int w = threadIdx.x >> 6, mq = w & 1, nq = w >> 1;
#pragma unroll
    for (int nt = 0; nt < 4; ++nt) {
        const int ncol = n0 + nq*64 + nt*16 + l15;
#pragma unroll
        for (int mt = 0; mt < 4; ++mt) {
            const int mrow = m0 + mq*64 + mt*16 + quad*4;
#pragma unroll
            for (int r = 0; r < 4; ++r)
                Cout[(size_t)(mrow + r) * DMODEL + ncol] = acc[mt][nt][r];
        }
    }
}

extern "C" void kernel_launch(void* const* d_in, const int* in_sizes, int n_in,
                              void* d_out, int out_size, void* d_ws, size_t ws_size,
                              hipStream_t stream) {
    const float* x  = (const float*)d_in[0];
    const float* PQ = (const float*)d_in[1];
    const float* PK = (const float*)d_in[2];
    const float* PV = (const float*)d_in[3];
    const float* PO = (const float*)d_in[4];
    float* out = (float*)d_out;
    char* ws = (char*)d_ws;

    const size_t MB = 1u << 20;
    u16* xb   = (u16*)(ws + 0 * MB);
    u16* Wqkv = (u16*)(ws + 16 * MB);
    u16* Wo   = (u16*)(ws + 22 * MB);
    u16* Qb   = (u16*)(ws + 24 * MB);
    u16* Kb   = (u16*)(ws + 40 * MB);
    u16* Vt   = (u16*)(ws + 56 * MB);
    u16* A2   = (u16*)(ws + 72 * MB);

    cvt_kernel<<<dim3(8192), dim3(256), 0, stream>>>(x,  xb,            2097152);
    cvt_kernel<<<dim3(1024), dim3(256), 0, stream>>>(PQ, Wqkv,           262144);
    cvt_kernel<<<dim3(1024), dim3(256), 0, stream>>>(PK, Wqkv + 1048576, 262144);
    cvt_kernel<<<dim3(1024), dim3(256), 0, stream>>>(PV, Wqkv + 2097152, 262144);
    cvt_kernel<<<dim3(1024), dim3(256), 0, stream>>>(PO, Wo,             262144);

    gemm_qkv_kernel<<<dim3(24, 64), dim3(256), 0, stream>>>(xb, Wqkv, Qb, Kb, Vt);

    attn_kernel<<<dim3(1024), dim3(256), 0, stream>>>(Qb, Kb, Vt, A2);

    gemm_oproj_kernel<<<dim3(8, 64), dim3(256), 0, stream>>>(A2, Wo, out);
}